// Round 1
// baseline (409.502 us; speedup 1.0000x reference)
//
#include <hip/hip_runtime.h>

#define NB    50000
#define BATCH 256
#define NCYC  20000

// ---------------- zero the scalar output (d_out is poisoned 0xAA) ----------
__global__ void zero_out_k(float* out) {
    if (threadIdx.x == 0) out[0] = 0.0f;
}

// ---------------- transpose c,s : [BATCH, NB] -> [NB, BATCH] ---------------
// 32x32 tiles, +1 pad to kill LDS bank conflicts. Both arrays in one kernel.
__global__ __launch_bounds__(256) void transpose2_k(
        const float* __restrict__ c, const float* __restrict__ s,
        float* __restrict__ ct, float* __restrict__ st) {
    __shared__ float tc[32][33];
    __shared__ float ts[32][33];
    const int tx = threadIdx.x;          // 0..31
    const int ty = threadIdx.y;          // 0..7
    const int x  = blockIdx.x * 32 + tx; // nb index
    const int yb = blockIdx.y * 32 + ty; // b index base
    if (x < NB) {
        #pragma unroll
        for (int j = 0; j < 32; j += 8) {
            const int y = yb + j;        // b < 256 always (grid.y = 8)
            tc[ty + j][tx] = c[(size_t)y * NB + x];
            ts[ty + j][tx] = s[(size_t)y * NB + x];
        }
    }
    __syncthreads();
    const int x2  = blockIdx.y * 32 + tx; // b index (coalesced store dim)
    const int y2b = blockIdx.x * 32 + ty; // nb index base
    #pragma unroll
    for (int j = 0; j < 32; j += 8) {
        const int y2 = y2b + j;
        if (y2 < NB) {
            ct[(size_t)y2 * BATCH + x2] = tc[tx][ty + j];
            st[(size_t)y2 * BATCH + x2] = ts[tx][ty + j];
        }
    }
}

// ---------------- row_start[r] = lower_bound(rows, r), r in [0, NCYC] ------
__global__ void row_starts_k(const int* __restrict__ rows, int E,
                             int* __restrict__ row_start) {
    const int r = blockIdx.x * blockDim.x + threadIdx.x;
    if (r > NCYC) return;
    int lo = 0, hi = E;
    while (lo < hi) {
        const int mid = (lo + hi) >> 1;
        if (rows[mid] < r) lo = mid + 1; else hi = mid;
    }
    row_start[r] = lo;
}

// ---------------- main: one wave (64 threads) per cycle row ----------------
// Thread t owns b = 4*t .. 4*t+3 ; float4 loads from transposed arrays.
__global__ __launch_bounds__(64) void kvl_main_k(
        const float* __restrict__ ct, const float* __restrict__ st,
        const float* __restrict__ signs, const int* __restrict__ inds,
        const int* __restrict__ row_start, float* __restrict__ out) {
    const int r     = blockIdx.x;
    const int start = row_start[r];
    const int end   = row_start[r + 1];
    const int tid   = threadIdx.x;        // 0..63

    float acc0 = 0.f, acc1 = 0.f, acc2 = 0.f, acc3 = 0.f;
    for (int e = start; e < end; ++e) {
        const int   idx = inds[e];        // uniform across wave
        const float sg  = signs[e];       // uniform across wave
        const float4 cv = *reinterpret_cast<const float4*>(
            &ct[(size_t)idx * BATCH + tid * 4]);
        const float4 sv = *reinterpret_cast<const float4*>(
            &st[(size_t)idx * BATCH + tid * 4]);
        acc0 += atan2f(sg * sv.x, cv.x);
        acc1 += atan2f(sg * sv.y, cv.y);
        acc2 += atan2f(sg * sv.z, cv.z);
        acc3 += atan2f(sg * sv.w, cv.w);
    }
    float v = fabsf(acc0) + fabsf(acc1) + fabsf(acc2) + fabsf(acc3);
    #pragma unroll
    for (int off = 32; off > 0; off >>= 1)
        v += __shfl_down(v, off, 64);
    if (tid == 0)
        atomicAdd(out, v * (1.0f / ((float)NCYC * (float)BATCH)));
}

// ---------------- fallback (no workspace): direct strided gather -----------
__global__ __launch_bounds__(256) void kvl_fallback_k(
        const float* __restrict__ c, const float* __restrict__ s,
        const float* __restrict__ signs, const int* __restrict__ inds,
        const int* __restrict__ rows, int E, float* __restrict__ out) {
    const int r = blockIdx.x;
    int lo = 0, hi = E;
    while (lo < hi) { const int m = (lo + hi) >> 1; if (rows[m] < r) lo = m + 1; else hi = m; }
    const int start = lo;
    hi = E;
    while (lo < hi) { const int m = (lo + hi) >> 1; if (rows[m] <= r) lo = m + 1; else hi = m; }
    const int end = lo;
    const int tid = threadIdx.x;          // tid == b
    float acc = 0.f;
    for (int e = start; e < end; ++e) {
        const int idx = inds[e];
        const float sg = signs[e];
        acc += atan2f(sg * s[(size_t)tid * NB + idx], c[(size_t)tid * NB + idx]);
    }
    float v = fabsf(acc);
    #pragma unroll
    for (int off = 32; off > 0; off >>= 1)
        v += __shfl_down(v, off, 64);
    __shared__ float wsum[4];
    if ((tid & 63) == 0) wsum[tid >> 6] = v;
    __syncthreads();
    if (tid == 0)
        atomicAdd(out, (wsum[0] + wsum[1] + wsum[2] + wsum[3]) *
                       (1.0f / ((float)NCYC * (float)BATCH)));
}

extern "C" void kernel_launch(void* const* d_in, const int* in_sizes, int n_in,
                              void* d_out, int out_size, void* d_ws, size_t ws_size,
                              hipStream_t stream) {
    const float* c       = (const float*)d_in[0];
    const float* s       = (const float*)d_in[1];
    const float* cysigns = (const float*)d_in[2];
    const int*   cyinds  = (const int*)d_in[3];
    const int*   cyrows  = (const int*)d_in[4];
    const int    E       = in_sizes[2];   // 160000
    float* out = (float*)d_out;

    zero_out_k<<<1, 64, 0, stream>>>(out);

    const size_t need = (size_t)2 * NB * BATCH * sizeof(float)
                      + (size_t)(NCYC + 1) * sizeof(int);
    if (ws_size >= need) {
        float* ct        = (float*)d_ws;
        float* st        = ct + (size_t)NB * BATCH;
        int*   row_start = (int*)(st + (size_t)NB * BATCH);

        dim3 tb(32, 8);
        dim3 tg((NB + 31) / 32, BATCH / 32);
        transpose2_k<<<tg, tb, 0, stream>>>(c, s, ct, st);
        row_starts_k<<<(NCYC + 1 + 255) / 256, 256, 0, stream>>>(cyrows, E, row_start);
        kvl_main_k<<<NCYC, 64, 0, stream>>>(ct, st, cysigns, cyinds, row_start, out);
    } else {
        kvl_fallback_k<<<NCYC, 256, 0, stream>>>(c, s, cysigns, cyinds, cyrows, E, out);
    }
}

// Round 2
// 206.253 us; speedup vs baseline: 1.9854x; 1.9854x over previous
//
#include <hip/hip_runtime.h>

#define NB    50000
#define NB4   (NB / 4)          // 12500, NB divisible by 4
#define BATCH 256
#define NCYC  20000

// ---------------- transpose c,s : [BATCH, NB] -> [NB, BATCH] ---------------
// 128(nb) x 32(b) tiles, float4 loads + float4 LDS writes. Block (32,8).
__global__ __launch_bounds__(256) void transpose2_k(
        const float4* __restrict__ c4, const float4* __restrict__ s4,
        float* __restrict__ ct, float* __restrict__ st) {
    __shared__ __align__(16) float tc[32][132];  // [b_local][nb_local], stride 132 (16B-aligned rows)
    __shared__ __align__(16) float ts[32][132];
    const int tx = threadIdx.x;               // 0..31
    const int ty = threadIdx.y;               // 0..7
    const int x4 = blockIdx.x * 32 + tx;      // float4 index along nb
    const int bb = blockIdx.y * 32;           // b tile base (grid.y = 8)

    if (x4 < NB4) {
        #pragma unroll
        for (int j = 0; j < 4; ++j) {
            const int yloc = ty + j * 8;      // b_local 0..31
            const float4 vc = c4[(size_t)(bb + yloc) * NB4 + x4];
            const float4 vs = s4[(size_t)(bb + yloc) * NB4 + x4];
            *reinterpret_cast<float4*>(&tc[yloc][4 * tx]) = vc;
            *reinterpret_cast<float4*>(&ts[yloc][4 * tx]) = vs;
        }
    }
    __syncthreads();
    const int nbBase = blockIdx.x * 128;
    #pragma unroll
    for (int jj = 0; jj < 16; ++jj) {
        const int nbl = ty + jj * 8;          // nb_local 0..127
        const int nb  = nbBase + nbl;
        if (nb < NB) {
            ct[(size_t)nb * BATCH + bb + tx] = tc[tx][nbl];
            st[(size_t)nb * BATCH + bb + tx] = ts[tx][nbl];
        }
    }
}

// ---------------- row_start[r] = lower_bound(rows, r), r in [0, NCYC] ------
__global__ void row_starts_k(const int* __restrict__ rows, int E,
                             int* __restrict__ row_start) {
    const int r = blockIdx.x * blockDim.x + threadIdx.x;
    if (r > NCYC) return;
    int lo = 0, hi = E;
    while (lo < hi) {
        const int mid = (lo + hi) >> 1;
        if (rows[mid] < r) lo = mid + 1; else hi = mid;
    }
    row_start[r] = lo;
}

// ---------------- main: one wave per cycle row, 4 waves/block --------------
// Lane t owns b = 4t..4t+3. Unroll-2 so 4 independent 1KB loads are in flight.
// NO atomics: per-row partial -> partials[r].
__global__ __launch_bounds__(256) void kvl_main_k(
        const float* __restrict__ ct, const float* __restrict__ st,
        const float* __restrict__ signs, const int* __restrict__ inds,
        const int* __restrict__ row_start, float* __restrict__ partials) {
    const int wave = threadIdx.x >> 6;
    const int lane = threadIdx.x & 63;
    const int r    = blockIdx.x * 4 + wave;   // grid = NCYC/4 = 5000
    const int start = row_start[r];
    const int end   = row_start[r + 1];

    float a0 = 0.f, a1 = 0.f, a2 = 0.f, a3 = 0.f;
    int e = start;
    for (; e + 2 <= end; e += 2) {
        const int   i0 = inds[e],     i1 = inds[e + 1];
        const float g0 = signs[e],    g1 = signs[e + 1];
        const float4 c0 = *reinterpret_cast<const float4*>(&ct[(size_t)i0 * BATCH + lane * 4]);
        const float4 s0 = *reinterpret_cast<const float4*>(&st[(size_t)i0 * BATCH + lane * 4]);
        const float4 c1 = *reinterpret_cast<const float4*>(&ct[(size_t)i1 * BATCH + lane * 4]);
        const float4 s1 = *reinterpret_cast<const float4*>(&st[(size_t)i1 * BATCH + lane * 4]);
        a0 += atan2f(g0 * s0.x, c0.x) + atan2f(g1 * s1.x, c1.x);
        a1 += atan2f(g0 * s0.y, c0.y) + atan2f(g1 * s1.y, c1.y);
        a2 += atan2f(g0 * s0.z, c0.z) + atan2f(g1 * s1.z, c1.z);
        a3 += atan2f(g0 * s0.w, c0.w) + atan2f(g1 * s1.w, c1.w);
    }
    if (e < end) {
        const int   i0 = inds[e];
        const float g0 = signs[e];
        const float4 c0 = *reinterpret_cast<const float4*>(&ct[(size_t)i0 * BATCH + lane * 4]);
        const float4 s0 = *reinterpret_cast<const float4*>(&st[(size_t)i0 * BATCH + lane * 4]);
        a0 += atan2f(g0 * s0.x, c0.x);
        a1 += atan2f(g0 * s0.y, c0.y);
        a2 += atan2f(g0 * s0.z, c0.z);
        a3 += atan2f(g0 * s0.w, c0.w);
    }
    float v = fabsf(a0) + fabsf(a1) + fabsf(a2) + fabsf(a3);
    #pragma unroll
    for (int off = 32; off > 0; off >>= 1)
        v += __shfl_down(v, off, 64);
    if (lane == 0) partials[r] = v;
}

// ---------------- final: single block reduces partials -> out[0] -----------
__global__ __launch_bounds__(1024) void reduce_k(
        const float* __restrict__ partials, float* __restrict__ out) {
    const int tid = threadIdx.x;
    float v = 0.f;
    for (int i = tid; i < NCYC; i += 1024) v += partials[i];
    #pragma unroll
    for (int off = 32; off > 0; off >>= 1)
        v += __shfl_down(v, off, 64);
    __shared__ float wsum[16];
    if ((tid & 63) == 0) wsum[tid >> 6] = v;
    __syncthreads();
    if (tid == 0) {
        float t = 0.f;
        #pragma unroll
        for (int w = 0; w < 16; ++w) t += wsum[w];
        out[0] = t * (1.0f / ((float)NCYC * (float)BATCH));
    }
}

// ---------------- fallback (no workspace): direct strided gather -----------
__global__ void zero_out_k(float* out) { if (threadIdx.x == 0) out[0] = 0.0f; }

__global__ __launch_bounds__(256) void kvl_fallback_k(
        const float* __restrict__ c, const float* __restrict__ s,
        const float* __restrict__ signs, const int* __restrict__ inds,
        const int* __restrict__ rows, int E, float* __restrict__ out) {
    const int r = blockIdx.x;
    int lo = 0, hi = E;
    while (lo < hi) { const int m = (lo + hi) >> 1; if (rows[m] < r) lo = m + 1; else hi = m; }
    const int start = lo;
    hi = E;
    while (lo < hi) { const int m = (lo + hi) >> 1; if (rows[m] <= r) lo = m + 1; else hi = m; }
    const int end = lo;
    const int tid = threadIdx.x;
    float acc = 0.f;
    for (int e = start; e < end; ++e) {
        const int idx = inds[e];
        const float sg = signs[e];
        acc += atan2f(sg * s[(size_t)tid * NB + idx], c[(size_t)tid * NB + idx]);
    }
    float v = fabsf(acc);
    #pragma unroll
    for (int off = 32; off > 0; off >>= 1)
        v += __shfl_down(v, off, 64);
    __shared__ float wsum[4];
    if ((tid & 63) == 0) wsum[tid >> 6] = v;
    __syncthreads();
    if (tid == 0)
        atomicAdd(out, (wsum[0] + wsum[1] + wsum[2] + wsum[3]) *
                       (1.0f / ((float)NCYC * (float)BATCH)));
}

extern "C" void kernel_launch(void* const* d_in, const int* in_sizes, int n_in,
                              void* d_out, int out_size, void* d_ws, size_t ws_size,
                              hipStream_t stream) {
    const float* c       = (const float*)d_in[0];
    const float* s       = (const float*)d_in[1];
    const float* cysigns = (const float*)d_in[2];
    const int*   cyinds  = (const int*)d_in[3];
    const int*   cyrows  = (const int*)d_in[4];
    const int    E       = in_sizes[2];   // 160000
    float* out = (float*)d_out;

    const size_t need = (size_t)2 * NB * BATCH * sizeof(float)
                      + (size_t)(NCYC + 1) * sizeof(int)
                      + (size_t)NCYC * sizeof(float);
    if (ws_size >= need) {
        float* ct        = (float*)d_ws;
        float* st        = ct + (size_t)NB * BATCH;
        int*   row_start = (int*)(st + (size_t)NB * BATCH);
        float* partials  = (float*)(row_start + (NCYC + 1));

        dim3 tb(32, 8);
        dim3 tg((NB4 + 31) / 32, BATCH / 32);  // (391, 8)
        transpose2_k<<<tg, tb, 0, stream>>>((const float4*)c, (const float4*)s, ct, st);
        row_starts_k<<<(NCYC + 1 + 255) / 256, 256, 0, stream>>>(cyrows, E, row_start);
        kvl_main_k<<<NCYC / 4, 256, 0, stream>>>(ct, st, cysigns, cyinds, row_start, partials);
        reduce_k<<<1, 1024, 0, stream>>>(partials, out);
    } else {
        zero_out_k<<<1, 64, 0, stream>>>(out);
        kvl_fallback_k<<<NCYC, 256, 0, stream>>>(c, s, cysigns, cyinds, cyrows, E, out);
    }
}

// Round 3
// 164.358 us; speedup vs baseline: 2.4915x; 1.2549x over previous
//
#include <hip/hip_runtime.h>
#include <hip/hip_fp16.h>

#define NB    50000
#define NB4   (NB / 4)          // 12500
#define BATCH 256
#define NCYC  20000

// ---- fused: transpose + atan2 -> theta[NB][BATCH] in fp16 -----------------
// Tiles: 128 nb x 32 b. Block (32,8). atan2 computed on the coalesced-load
// side (one eval per (b, branch) TOTAL thanks to atan2(g*s,c) = g*atan2(s,c)).
__global__ __launch_bounds__(256) void theta_k(
        const float4* __restrict__ c4, const float4* __restrict__ s4,
        unsigned short* __restrict__ th) {
    __shared__ unsigned short t[32][130];   // [b_local][nb_local], pad->odd stride
    const int tx = threadIdx.x;             // 0..31  (nb4 within tile)
    const int ty = threadIdx.y;             // 0..7
    const int x4 = blockIdx.x * 32 + tx;    // float4 index along nb
    const int bb = blockIdx.y * 32;         // b tile base (grid.y = 8)

    if (x4 < NB4) {
        #pragma unroll
        for (int j = 0; j < 4; ++j) {
            const int bl = ty + j * 8;      // b_local 0..31
            const float4 vc = c4[(size_t)(bb + bl) * NB4 + x4];
            const float4 vs = s4[(size_t)(bb + bl) * NB4 + x4];
            ushort4 p;
            p.x = __half_as_ushort(__float2half(atan2f(vs.x, vc.x)));
            p.y = __half_as_ushort(__float2half(atan2f(vs.y, vc.y)));
            p.z = __half_as_ushort(__float2half(atan2f(vs.z, vc.z)));
            p.w = __half_as_ushort(__float2half(atan2f(vs.w, vc.w)));
            *reinterpret_cast<ushort4*>(&t[bl][4 * tx]) = p;   // 8B LDS store
        }
    }
    __syncthreads();
    // write phase: each thread stores ushort2 (2 consecutive b) -> 64B segs
    const int u    = ty * 32 + tx;          // 0..255
    const int b2   = u & 15;                // b = bb + 2*b2 (+1)
    const int nbl0 = u >> 4;                // 0..15
    const int nbBase = blockIdx.x * 128;
    #pragma unroll
    for (int jj = 0; jj < 8; ++jj) {
        const int nbl = nbl0 + jj * 16;     // 0..127
        const int nb  = nbBase + nbl;
        if (nb < NB) {
            ushort2 v;
            v.x = t[2 * b2][nbl];
            v.y = t[2 * b2 + 1][nbl];
            *reinterpret_cast<ushort2*>(&th[(size_t)nb * BATCH + bb + 2 * b2]) = v;
        }
    }
}

// ---- row_start[r] = lower_bound(rows, r), r in [0, NCYC] ------------------
__global__ void row_starts_k(const int* __restrict__ rows, int E,
                             int* __restrict__ row_start) {
    const int r = blockIdx.x * blockDim.x + threadIdx.x;
    if (r > NCYC) return;
    int lo = 0, hi = E;
    while (lo < hi) {
        const int mid = (lo + hi) >> 1;
        if (rows[mid] < r) lo = mid + 1; else hi = mid;
    }
    row_start[r] = lo;
}

// ---- main: one wave per row; lane owns 4 b; pure gather + sign-fma --------
__global__ __launch_bounds__(256) void kvl_main_k(
        const unsigned short* __restrict__ th,
        const float* __restrict__ signs, const int* __restrict__ inds,
        const int* __restrict__ row_start, float* __restrict__ partials) {
    const int wave = threadIdx.x >> 6;
    const int lane = threadIdx.x & 63;
    const int r    = blockIdx.x * 4 + wave;   // grid = NCYC/4
    const int start = row_start[r];
    const int end   = row_start[r + 1];

    float a0 = 0.f, a1 = 0.f, a2 = 0.f, a3 = 0.f;
    int e = start;
    for (; e + 2 <= end; e += 2) {
        const int   i0 = inds[e],  i1 = inds[e + 1];
        const float g0 = signs[e], g1 = signs[e + 1];
        const ushort4 u0 = *reinterpret_cast<const ushort4*>(&th[(size_t)i0 * BATCH + lane * 4]);
        const ushort4 u1 = *reinterpret_cast<const ushort4*>(&th[(size_t)i1 * BATCH + lane * 4]);
        a0 += g0 * __half2float(__ushort_as_half(u0.x)) + g1 * __half2float(__ushort_as_half(u1.x));
        a1 += g0 * __half2float(__ushort_as_half(u0.y)) + g1 * __half2float(__ushort_as_half(u1.y));
        a2 += g0 * __half2float(__ushort_as_half(u0.z)) + g1 * __half2float(__ushort_as_half(u1.z));
        a3 += g0 * __half2float(__ushort_as_half(u0.w)) + g1 * __half2float(__ushort_as_half(u1.w));
    }
    if (e < end) {
        const int   i0 = inds[e];
        const float g0 = signs[e];
        const ushort4 u0 = *reinterpret_cast<const ushort4*>(&th[(size_t)i0 * BATCH + lane * 4]);
        a0 += g0 * __half2float(__ushort_as_half(u0.x));
        a1 += g0 * __half2float(__ushort_as_half(u0.y));
        a2 += g0 * __half2float(__ushort_as_half(u0.z));
        a3 += g0 * __half2float(__ushort_as_half(u0.w));
    }
    float v = fabsf(a0) + fabsf(a1) + fabsf(a2) + fabsf(a3);
    #pragma unroll
    for (int off = 32; off > 0; off >>= 1)
        v += __shfl_down(v, off, 64);
    if (lane == 0) partials[r] = v;
}

// ---- final: single block reduces partials -> out[0] -----------------------
__global__ __launch_bounds__(1024) void reduce_k(
        const float* __restrict__ partials, float* __restrict__ out) {
    const int tid = threadIdx.x;
    float v = 0.f;
    for (int i = tid; i < NCYC; i += 1024) v += partials[i];
    #pragma unroll
    for (int off = 32; off > 0; off >>= 1)
        v += __shfl_down(v, off, 64);
    __shared__ float wsum[16];
    if ((tid & 63) == 0) wsum[tid >> 6] = v;
    __syncthreads();
    if (tid == 0) {
        float t = 0.f;
        #pragma unroll
        for (int w = 0; w < 16; ++w) t += wsum[w];
        out[0] = t * (1.0f / ((float)NCYC * (float)BATCH));
    }
}

// ---- fallback (no workspace): direct strided gather -----------------------
__global__ void zero_out_k(float* out) { if (threadIdx.x == 0) out[0] = 0.0f; }

__global__ __launch_bounds__(256) void kvl_fallback_k(
        const float* __restrict__ c, const float* __restrict__ s,
        const float* __restrict__ signs, const int* __restrict__ inds,
        const int* __restrict__ rows, int E, float* __restrict__ out) {
    const int r = blockIdx.x;
    int lo = 0, hi = E;
    while (lo < hi) { const int m = (lo + hi) >> 1; if (rows[m] < r) lo = m + 1; else hi = m; }
    const int start = lo;
    hi = E;
    while (lo < hi) { const int m = (lo + hi) >> 1; if (rows[m] <= r) lo = m + 1; else hi = m; }
    const int end = lo;
    const int tid = threadIdx.x;
    float acc = 0.f;
    for (int e = start; e < end; ++e) {
        const int idx = inds[e];
        const float sg = signs[e];
        acc += atan2f(sg * s[(size_t)tid * NB + idx], c[(size_t)tid * NB + idx]);
    }
    float v = fabsf(acc);
    #pragma unroll
    for (int off = 32; off > 0; off >>= 1)
        v += __shfl_down(v, off, 64);
    __shared__ float wsum[4];
    if ((tid & 63) == 0) wsum[tid >> 6] = v;
    __syncthreads();
    if (tid == 0)
        atomicAdd(out, (wsum[0] + wsum[1] + wsum[2] + wsum[3]) *
                       (1.0f / ((float)NCYC * (float)BATCH)));
}

extern "C" void kernel_launch(void* const* d_in, const int* in_sizes, int n_in,
                              void* d_out, int out_size, void* d_ws, size_t ws_size,
                              hipStream_t stream) {
    const float* c       = (const float*)d_in[0];
    const float* s       = (const float*)d_in[1];
    const float* cysigns = (const float*)d_in[2];
    const int*   cyinds  = (const int*)d_in[3];
    const int*   cyrows  = (const int*)d_in[4];
    const int    E       = in_sizes[2];   // 160000
    float* out = (float*)d_out;

    const size_t th_elems = (size_t)NB * BATCH;           // 12.8M ushorts
    const size_t need = th_elems * sizeof(unsigned short)
                      + (size_t)(NCYC + 1) * sizeof(int)
                      + (size_t)NCYC * sizeof(float);
    if (ws_size >= need) {
        unsigned short* th  = (unsigned short*)d_ws;
        int*   row_start    = (int*)(th + th_elems);
        float* partials     = (float*)(row_start + (NCYC + 1));

        dim3 tb(32, 8);
        dim3 tg((NB4 + 31) / 32, BATCH / 32);  // (391, 8)
        theta_k<<<tg, tb, 0, stream>>>((const float4*)c, (const float4*)s, th);
        row_starts_k<<<(NCYC + 1 + 255) / 256, 256, 0, stream>>>(cyrows, E, row_start);
        kvl_main_k<<<NCYC / 4, 256, 0, stream>>>(th, cysigns, cyinds, row_start, partials);
        reduce_k<<<1, 1024, 0, stream>>>(partials, out);
    } else {
        zero_out_k<<<1, 64, 0, stream>>>(out);
        kvl_fallback_k<<<NCYC, 256, 0, stream>>>(c, s, cysigns, cyinds, cyrows, E, out);
    }
}